// Round 14
// baseline (571.096 us; speedup 1.0000x reference)
//
#include <hip/hip_runtime.h>

#define NG 128
#define NN 1024
#define KK 16
#define HALF 512          // candidates per scan-half
#define SLOPE 0.01f
#define FINF 3.0e38f

typedef unsigned short u16;

__device__ __forceinline__ float leaky(float v) {
    return v >= 0.0f ? v : SLOPE * v;
}

// branchless stable sorted insert (ascending by d; ties keep existing = earlier j)
__device__ __forceinline__ void sorted_insert(float (&bd)[KK], int (&bi)[KK],
                                              float d, int j) {
    bool c[KK];
#pragma unroll
    for (int t = 0; t < KK; ++t) c[t] = d < bd[t];
#pragma unroll
    for (int t = KK - 1; t >= 1; --t) {
        bd[t] = c[t] ? (c[t - 1] ? bd[t - 1] : d) : bd[t];
        bi[t] = c[t] ? (c[t - 1] ? bi[t - 1] : j) : bi[t];
    }
    bd[0] = c[0] ? d : bd[0];
    bi[0] = c[0] ? j : bi[0];
}

// kNN body: med3-chain distance-only top-16 (uniform, branch-free), cross-half
// d16 merge, rescan-recovery of indices, final (d,j)-stable selection.
// Thread layout: tid&127 = query-within-chunk, tid>>7 = candidate half.
__device__ __forceinline__ void knn_body(const float4* __restrict__ posq,
                                         float* __restrict__ pub_d,   // [256*16]
                                         u16* __restrict__ pend_j,    // [256*17]
                                         int g, int chunk, int tid,
                                         u16* __restrict__ idx) {
    const int q = tid & 127;
    const int half = tid >> 7;
    const int i = chunk * 128 + q;
    const int jlo = half * HALF;

    const float4 meq = posq[i];
    const float mex = -2.0f * meq.x, mey = -2.0f * meq.y, mez = -2.0f * meq.z;
    const float mew = meq.w;

    // ---- Phase 1: 16 smallest distances via med3 chain (no divergence) ----
    float bd[KK];
#pragma unroll
    for (int t = 0; t < KK; ++t) bd[t] = FINF;

    for (int j0 = jlo; j0 < jlo + HALF; j0 += 8) {
        float4 p[8];
#pragma unroll
        for (int u = 0; u < 8; ++u) p[u] = posq[j0 + u];
#pragma unroll
        for (int u = 0; u < 8; ++u) {
            const int j = j0 + u;
            float d2 = fmaf(mex, p[u].x, fmaf(mey, p[u].y,
                          fmaf(mez, p[u].z, mew + p[u].w)));
            d2 = (j == i) ? FINF : d2;
            // sorted-ascending insert: bd[t] = median(d2, bd[t-1], bd[t])
#pragma unroll
            for (int t = KK - 1; t >= 1; --t)
                bd[t] = __builtin_amdgcn_fmed3f(d2, bd[t - 1], bd[t]);
            bd[0] = fminf(bd[0], d2);
        }
    }

    // ---- publish own sorted 16; compute global d16 with partner ----
#pragma unroll
    for (int t = 0; t < KK; ++t) pub_d[tid + 256 * t] = bd[t];
    __syncthreads();

    float d16;
    {
        const int pr = tid ^ 128;
        int ia = 0, ib = 0;
        float v = FINF;
#pragma unroll
        for (int k = 0; k < KK; ++k) {
            float da = pub_d[tid + 256 * ia];
            float db = pub_d[pr + 256 * ib];
            bool ta = da <= db;
            v = ta ? da : db;
            ia += ta ? 1 : 0;
            ib += ta ? 0 : 1;
        }
        d16 = v;
    }
    __syncthreads();   // pub_d reads done; safe to overwrite in phase 2

    // ---- Phase 2: rescan, collect (d,j) with d <= d16 (j-order, cap 16) ----
    // Winners (16 smallest by (d,j)) provably lie within the first 16 j-ordered
    // passers of their half: non-winner ties have larger j than every winning tie.
    int cnt = 0;
    for (int j0 = jlo; j0 < jlo + HALF; j0 += 8) {
        float4 p[8];
#pragma unroll
        for (int u = 0; u < 8; ++u) p[u] = posq[j0 + u];
#pragma unroll
        for (int u = 0; u < 8; ++u) {
            const int j = j0 + u;
            float d2 = fmaf(mex, p[u].x, fmaf(mey, p[u].y,
                          fmaf(mez, p[u].z, mew + p[u].w)));
            d2 = (j == i) ? FINF : d2;
            if (d2 <= d16 && cnt < KK) {
                pub_d[tid + 256 * cnt] = d2;
                pend_j[tid + 256 * cnt] = (u16)j;
                ++cnt;
            }
        }
    }
    pend_j[tid + 256 * 16] = (u16)cnt;
    __syncthreads();

    // ---- final selection: stable (d, then j) top-16 over both halves ----
    if (tid < 128) {
        float sd[KK];
        int si[KK];
#pragma unroll
        for (int t = 0; t < KK; ++t) { sd[t] = FINF; si[t] = 0; }
        const int c0 = pend_j[tid + 256 * 16];
        const int c1 = pend_j[(tid + 128) + 256 * 16];
#pragma unroll 1
        for (int s = 0; s < KK; ++s) {
            bool a = s < c0;
            float d = a ? pub_d[tid + 256 * s] : FINF;
            int j = pend_j[tid + 256 * s];
            if (__any(d < sd[KK - 1])) sorted_insert(sd, si, d, j);
        }
#pragma unroll 1
        for (int s = 0; s < KK; ++s) {
            bool a = s < c1;
            float d = a ? pub_d[(tid + 128) + 256 * s] : FINF;
            int j = pend_j[(tid + 128) + 256 * s];
            if (__any(d < sd[KK - 1])) sorted_insert(sd, si, d, j);
        }
        unsigned int pack[8];
#pragma unroll
        for (int t = 0; t < KK; t += 2)
            pack[t >> 1] = (unsigned int)si[t] | ((unsigned int)si[t + 1] << 16);
        uint4* o4 = (uint4*)(idx + ((size_t)g * NN + i) * KK);
        o4[0] = make_uint4(pack[0], pack[1], pack[2], pack[3]);
        o4[1] = make_uint4(pack[4], pack[5], pack[6], pack[7]);
    }
}

// ---------------- kNN on xyz -> idx (8 blocks/graph, 128 queries each) -------------
__global__ __launch_bounds__(256) void knn1(
    const float* __restrict__ x, u16* __restrict__ idx)
{
    __shared__ float4 posq[NN];           // 16 KB
    __shared__ float pub_d[256 * 16];     // 16 KB (published lists, then phase-2 d)
    __shared__ u16 pend_j[256 * 17];      // 8.5 KB (phase-2 j + cnt row)

    const int g = blockIdx.x >> 3;
    const int chunk = blockIdx.x & 7;
    const int tid = threadIdx.x;

    for (int n = tid; n < NN; n += 256) {
        const float* xp = x + (size_t)(g * NN + n) * 3;
        float px = xp[0], py = xp[1], pz = xp[2];
        posq[n] = make_float4(px, py, pz, px * px + py * py + pz * pz);
    }
    __syncthreads();

    knn_body(posq, pub_d, pend_j, g, chunk, tid, idx);
}

// ---------------- kNN on h1[:, :3] -> idx ------------------------------------------
__global__ __launch_bounds__(256) void knn2(
    const float* __restrict__ h1, u16* __restrict__ idx)
{
    __shared__ float4 posq[NN];
    __shared__ float pub_d[256 * 16];
    __shared__ u16 pend_j[256 * 17];

    const int g = blockIdx.x >> 3;
    const int chunk = blockIdx.x & 7;
    const int tid = threadIdx.x;

    for (int n = tid; n < NN; n += 256) {
        const float4 a = *(const float4*)(h1 + (size_t)(g * NN + n) * 16);
        posq[n] = make_float4(a.x, a.y, a.z, a.x * a.x + a.y * a.y + a.z * a.z);
    }
    __syncthreads();

    knn_body(posq, pub_d, pend_j, g, chunk, tid, idx);
}

// ---- shared edge pass: acc[o] = sum_t leaky(b2[o] + sum_f leaky(s1[f]+u_j[f]) * W2[f,o])
__device__ __forceinline__ void edge_pass(
    const float* __restrict__ u_lds,   // [NN*16] per-node layer-1 hi contributions
    const float (&s1)[16],
    const u16* __restrict__ my_idx,
    const float* __restrict__ W2,      // [16*16] global
    const float* __restrict__ b2,      // [16] global
    float* __restrict__ out_row)
{
#pragma unroll 1
    for (int half = 0; half < 2; ++half) {
        float4 w2h[16][2];
#pragma unroll
        for (int f = 0; f < 16; ++f) {
            w2h[f][0] = *(const float4*)(W2 + f * 16 + half * 8);
            w2h[f][1] = *(const float4*)(W2 + f * 16 + half * 8 + 4);
        }
        float bb[8];
#pragma unroll
        for (int oo = 0; oo < 8; ++oo) bb[oo] = b2[half * 8 + oo];

        float acc[8];
#pragma unroll
        for (int oo = 0; oo < 8; ++oo) acc[oo] = 0.0f;

#pragma unroll 1
        for (int t = 0; t < KK; ++t) {
            const int j = my_idx[t];
            const float4* uj4 = (const float4*)(u_lds + j * 16);
            float4 u0 = uj4[0], u1 = uj4[1], u2 = uj4[2], u3 = uj4[3];
            float m1[16];
            m1[0]  = leaky(s1[0]  + u0.x);  m1[1]  = leaky(s1[1]  + u0.y);
            m1[2]  = leaky(s1[2]  + u0.z);  m1[3]  = leaky(s1[3]  + u0.w);
            m1[4]  = leaky(s1[4]  + u1.x);  m1[5]  = leaky(s1[5]  + u1.y);
            m1[6]  = leaky(s1[6]  + u1.z);  m1[7]  = leaky(s1[7]  + u1.w);
            m1[8]  = leaky(s1[8]  + u2.x);  m1[9]  = leaky(s1[9]  + u2.y);
            m1[10] = leaky(s1[10] + u2.z);  m1[11] = leaky(s1[11] + u2.w);
            m1[12] = leaky(s1[12] + u3.x);  m1[13] = leaky(s1[13] + u3.y);
            m1[14] = leaky(s1[14] + u3.z);  m1[15] = leaky(s1[15] + u3.w);

            float v[8];
#pragma unroll
            for (int oo = 0; oo < 8; ++oo) v[oo] = bb[oo];
#pragma unroll
            for (int f = 0; f < 16; ++f) {
                float4 wa = w2h[f][0], wb = w2h[f][1];
                v[0] += m1[f] * wa.x;  v[1] += m1[f] * wa.y;
                v[2] += m1[f] * wa.z;  v[3] += m1[f] * wa.w;
                v[4] += m1[f] * wb.x;  v[5] += m1[f] * wb.y;
                v[6] += m1[f] * wb.z;  v[7] += m1[f] * wb.w;
            }
#pragma unroll
            for (int oo = 0; oo < 8; ++oo) acc[oo] += leaky(v[oo]);
        }
        float4* o4 = (float4*)(out_row + half * 8);
        o4[0] = make_float4(acc[0], acc[1], acc[2], acc[3]);
        o4[1] = make_float4(acc[4], acc[5], acc[6], acc[7]);
    }
}

// ---------------- EdgeConv 1: [6->16->16], u-precompute + reg-resident weights -----
__global__ __launch_bounds__(256) void conv1(
    const float* __restrict__ x,
    const u16* __restrict__ idx,
    const float* __restrict__ W1,   // [6*16]
    const float* __restrict__ b1,
    const float* __restrict__ W2,   // [16*16]
    const float* __restrict__ b2,
    float* __restrict__ h1)
{
    __shared__ float u_lds[NN * 16];   // 64 KB

    const int g = blockIdx.x >> 2;
    const int chunk = blockIdx.x & 3;
    const int tid = threadIdx.x;

    float wlo[3][16], whi[3][16];
#pragma unroll
    for (int c = 0; c < 3; ++c) {
#pragma unroll
        for (int q = 0; q < 4; ++q) {
            *(float4*)&wlo[c][q * 4] = *(const float4*)(W1 + c * 16 + q * 4);
            *(float4*)&whi[c][q * 4] = *(const float4*)(W1 + (3 + c) * 16 + q * 4);
        }
    }

#pragma unroll 1
    for (int r = 0; r < 4; ++r) {
        const int n = r * 256 + tid;
        const float* xp = x + ((size_t)g * NN + n) * 3;
        float px = xp[0], py = xp[1], pz = xp[2];
        float4* un = (float4*)(u_lds + n * 16);
#pragma unroll
        for (int q = 0; q < 4; ++q) {
            float4 uv;
            uv.x = px * whi[0][q * 4 + 0] + py * whi[1][q * 4 + 0] + pz * whi[2][q * 4 + 0];
            uv.y = px * whi[0][q * 4 + 1] + py * whi[1][q * 4 + 1] + pz * whi[2][q * 4 + 1];
            uv.z = px * whi[0][q * 4 + 2] + py * whi[1][q * 4 + 2] + pz * whi[2][q * 4 + 2];
            uv.w = px * whi[0][q * 4 + 3] + py * whi[1][q * 4 + 3] + pz * whi[2][q * 4 + 3];
            un[q] = uv;
        }
    }

    const int i = chunk * 256 + tid;
    const float* mp = x + ((size_t)g * NN + i) * 3;
    const float mxx = mp[0], myy = mp[1], mzz = mp[2];
    float s1[16];
#pragma unroll
    for (int o = 0; o < 16; ++o) {
        s1[o] = b1[o] + mxx * (wlo[0][o] - whi[0][o])
                      + myy * (wlo[1][o] - whi[1][o])
                      + mzz * (wlo[2][o] - whi[2][o]);
    }
    __syncthreads();

    edge_pass(u_lds, s1, idx + (size_t)(g * NN + i) * KK, W2, b2,
              h1 + (size_t)(g * NN + i) * 16);
}

// ---------------- EdgeConv 2: [32->16->16], in-place u over the h1 LDS tile --------
__global__ __launch_bounds__(256) void conv2(
    const float* __restrict__ h1,
    const u16* __restrict__ idx,
    const float* __restrict__ W1,   // [32*16]
    const float* __restrict__ b1,
    const float* __restrict__ W2,
    const float* __restrict__ b2,
    float* __restrict__ h2)
{
    __shared__ float tile[NN * 16];
    __shared__ float w1s[32 * 16];
    __shared__ float b1s[16];

    const int g = blockIdx.x >> 2;
    const int chunk = blockIdx.x & 3;
    const int tid = threadIdx.x;

    w1s[tid] = W1[tid];
    w1s[256 + tid] = W1[256 + tid];
    if (tid < 16) b1s[tid] = b1[tid];

    float4* t4 = (float4*)tile;
    const float4* src4 = (const float4*)(h1 + (size_t)g * NN * 16);
    for (int t = tid; t < NN * 4; t += 256) t4[t] = src4[t];
    __syncthreads();

    float s1[16];
#pragma unroll 1
    for (int r = 0; r < 4; ++r) {
        asm volatile("" ::: "memory");
        const int n = r * 256 + tid;
        float4 x0 = t4[n * 4 + 0], x1 = t4[n * 4 + 1];
        float4 x2 = t4[n * 4 + 2], x3 = t4[n * 4 + 3];
        float xr[16] = {x0.x, x0.y, x0.z, x0.w, x1.x, x1.y, x1.z, x1.w,
                        x2.x, x2.y, x2.z, x2.w, x3.x, x3.y, x3.z, x3.w};
        float uo[16];
#pragma unroll
        for (int og = 0; og < 4; ++og) {
            float a0 = 0.f, a1 = 0.f, a2 = 0.f, a3 = 0.f;
#pragma unroll
            for (int f = 0; f < 16; ++f) {
                float4 wv = *(const float4*)(w1s + (16 + f) * 16 + og * 4);
                a0 += xr[f] * wv.x; a1 += xr[f] * wv.y;
                a2 += xr[f] * wv.z; a3 += xr[f] * wv.w;
            }
            uo[og * 4 + 0] = a0; uo[og * 4 + 1] = a1;
            uo[og * 4 + 2] = a2; uo[og * 4 + 3] = a3;
        }
        if (r == chunk) {
            float t1[16];
#pragma unroll
            for (int og = 0; og < 4; ++og) {
                float a0 = 0.f, a1 = 0.f, a2 = 0.f, a3 = 0.f;
#pragma unroll
                for (int f = 0; f < 16; ++f) {
                    float4 wv = *(const float4*)(w1s + f * 16 + og * 4);
                    a0 += xr[f] * wv.x; a1 += xr[f] * wv.y;
                    a2 += xr[f] * wv.z; a3 += xr[f] * wv.w;
                }
                t1[og * 4 + 0] = a0; t1[og * 4 + 1] = a1;
                t1[og * 4 + 2] = a2; t1[og * 4 + 3] = a3;
            }
#pragma unroll
            for (int o = 0; o < 16; ++o) s1[o] = b1s[o] + t1[o] - uo[o];
        }
        t4[n * 4 + 0] = make_float4(uo[0], uo[1], uo[2], uo[3]);
        t4[n * 4 + 1] = make_float4(uo[4], uo[5], uo[6], uo[7]);
        t4[n * 4 + 2] = make_float4(uo[8], uo[9], uo[10], uo[11]);
        t4[n * 4 + 3] = make_float4(uo[12], uo[13], uo[14], uo[15]);
    }
    __syncthreads();

    const int i = chunk * 256 + tid;
    edge_pass(tile, s1, idx + (size_t)(g * NN + i) * KK, W2, b2,
              h2 + (size_t)(g * NN + i) * 16);
}

// ---------- Post-MLP [35->16->16] + block-partial pooling --------------------------
__global__ __launch_bounds__(256) void post_pool(
    const float* __restrict__ x,
    const float* __restrict__ h1,
    const float* __restrict__ h2,
    const float* __restrict__ Wp1, const float* __restrict__ bp1,
    const float* __restrict__ Wp2, const float* __restrict__ bp2,
    float* __restrict__ partial)
{
    __shared__ float wp1[35 * 16];
    __shared__ float wp2[16 * 16];
    __shared__ float sbp1[16], sbp2[16];
    __shared__ float red[3][4][16];

    const int g = blockIdx.x >> 2;
    const int chunk = blockIdx.x & 3;
    const int tid = threadIdx.x;

    wp2[tid] = Wp2[tid];
    for (int t = tid; t < 560; t += 256) wp1[t] = Wp1[t];
    if (tid < 16) { sbp1[tid] = bp1[tid]; sbp2[tid] = bp2[tid]; }
    __syncthreads();

    const int i = chunk * 256 + tid;
    const float* xp = x + (size_t)(g * NN + i) * 3;
    const float x0 = xp[0], x1 = xp[1], x2 = xp[2];
    const float4* p1v = (const float4*)(h1 + (size_t)(g * NN + i) * 16);
    float4 a0 = p1v[0], a1 = p1v[1], a2 = p1v[2], a3 = p1v[3];
    const float4* p2v = (const float4*)(h2 + (size_t)(g * NN + i) * 16);
    float4 c0 = p2v[0], c1 = p2v[1], c2 = p2v[2], c3 = p2v[3];

    float p1[16];
#pragma unroll
    for (int o = 0; o < 16; ++o) {
        float v = sbp1[o];
        v += x0 * wp1[0 * 16 + o];
        v += x1 * wp1[1 * 16 + o];
        v += x2 * wp1[2 * 16 + o];
        v += a0.x * wp1[3 * 16 + o];   v += a0.y * wp1[4 * 16 + o];
        v += a0.z * wp1[5 * 16 + o];   v += a0.w * wp1[6 * 16 + o];
        v += a1.x * wp1[7 * 16 + o];   v += a1.y * wp1[8 * 16 + o];
        v += a1.z * wp1[9 * 16 + o];   v += a1.w * wp1[10 * 16 + o];
        v += a2.x * wp1[11 * 16 + o];  v += a2.y * wp1[12 * 16 + o];
        v += a2.z * wp1[13 * 16 + o];  v += a2.w * wp1[14 * 16 + o];
        v += a3.x * wp1[15 * 16 + o];  v += a3.y * wp1[16 * 16 + o];
        v += a3.z * wp1[17 * 16 + o];  v += a3.w * wp1[18 * 16 + o];
        v += c0.x * wp1[19 * 16 + o];  v += c0.y * wp1[20 * 16 + o];
        v += c0.z * wp1[21 * 16 + o];  v += c0.w * wp1[22 * 16 + o];
        v += c1.x * wp1[23 * 16 + o];  v += c1.y * wp1[24 * 16 + o];
        v += c1.z * wp1[25 * 16 + o];  v += c1.w * wp1[26 * 16 + o];
        v += c2.x * wp1[27 * 16 + o];  v += c2.y * wp1[28 * 16 + o];
        v += c2.z * wp1[29 * 16 + o];  v += c2.w * wp1[30 * 16 + o];
        v += c3.x * wp1[31 * 16 + o];  v += c3.y * wp1[32 * 16 + o];
        v += c3.z * wp1[33 * 16 + o];  v += c3.w * wp1[34 * 16 + o];
        p1[o] = leaky(v);
    }

    float mn[16], mx[16], sm[16];
#pragma unroll
    for (int o = 0; o < 16; ++o) {
        float v = sbp2[o];
#pragma unroll
        for (int f = 0; f < 16; ++f) v += p1[f] * wp2[f * 16 + o];
        float p2 = leaky(v);
        mn[o] = p2; mx[o] = p2; sm[o] = p2;
    }

#pragma unroll
    for (int off = 32; off >= 1; off >>= 1) {
#pragma unroll
        for (int o = 0; o < 16; ++o) {
            mn[o] = fminf(mn[o], __shfl_xor(mn[o], off));
            mx[o] = fmaxf(mx[o], __shfl_xor(mx[o], off));
            sm[o] += __shfl_xor(sm[o], off);
        }
    }
    const int wave = tid >> 6;
    const int lane = tid & 63;
    if (lane == 0) {
#pragma unroll
        for (int o = 0; o < 16; ++o) {
            red[0][wave][o] = mn[o];
            red[1][wave][o] = mx[o];
            red[2][wave][o] = sm[o];
        }
    }
    __syncthreads();

    if (tid < 48) {
        const int stat = tid >> 4, o = tid & 15;
        float v;
        if (stat == 0)
            v = fminf(fminf(red[0][0][o], red[0][1][o]), fminf(red[0][2][o], red[0][3][o]));
        else if (stat == 1)
            v = fmaxf(fmaxf(red[1][0][o], red[1][1][o]), fmaxf(red[1][2][o], red[1][3][o]));
        else
            v = red[2][0][o] + red[2][1][o] + red[2][2][o] + red[2][3][o];
        partial[blockIdx.x * 48 + tid] = v;
    }
}

// -------- Finalize: combine 4 block-partials per graph + readout [48->128->10] -----
__global__ __launch_bounds__(128) void finalize(
    const float* __restrict__ partial,
    const float* __restrict__ Wr1, const float* __restrict__ br1,
    const float* __restrict__ Wr2, const float* __restrict__ br2,
    float* __restrict__ out)
{
    __shared__ float pooled[48];
    __shared__ float hidden[128];

    const int g = blockIdx.x;
    const int tid = threadIdx.x;

    if (tid < 48) {
        const int stat = tid >> 4;
        float a = partial[(g * 4 + 0) * 48 + tid];
        float b = partial[(g * 4 + 1) * 48 + tid];
        float c = partial[(g * 4 + 2) * 48 + tid];
        float d = partial[(g * 4 + 3) * 48 + tid];
        float v;
        if (stat == 0)      v = fminf(fminf(a, b), fminf(c, d));
        else if (stat == 1) v = fmaxf(fmaxf(a, b), fmaxf(c, d));
        else                v = (a + b + c + d) * (1.0f / NN);
        pooled[tid] = v;
    }
    __syncthreads();

    {
        float v = br1[tid];
#pragma unroll
        for (int f = 0; f < 48; ++f) v += pooled[f] * Wr1[f * 128 + tid];
        hidden[tid] = leaky(v);
    }
    __syncthreads();

    if (tid < 10) {
        float v = br2[tid];
#pragma unroll
        for (int f = 0; f < 128; ++f) v += hidden[f] * Wr2[f * 10 + tid];
        out[g * 10 + tid] = v;
    }
}

extern "C" void kernel_launch(void* const* d_in, const int* in_sizes, int n_in,
                              void* d_out, int out_size, void* d_ws, size_t ws_size,
                              hipStream_t stream) {
    const float* x   = (const float*)d_in[0];
    const float* W1a = (const float*)d_in[2];
    const float* b1a = (const float*)d_in[3];
    const float* W2a = (const float*)d_in[4];
    const float* b2a = (const float*)d_in[5];
    const float* W1b = (const float*)d_in[6];
    const float* b1b = (const float*)d_in[7];
    const float* W2b = (const float*)d_in[8];
    const float* b2b = (const float*)d_in[9];
    const float* Wp1 = (const float*)d_in[10];
    const float* bp1 = (const float*)d_in[11];
    const float* Wp2 = (const float*)d_in[12];
    const float* bp2 = (const float*)d_in[13];
    const float* Wr1 = (const float*)d_in[14];
    const float* br1 = (const float*)d_in[15];
    const float* Wr2 = (const float*)d_in[16];
    const float* br2 = (const float*)d_in[17];
    float* out = (float*)d_out;

    float* h1 = (float*)d_ws;                         // 8 MB
    float* h2 = h1 + (size_t)NG * NN * 16;            // 8 MB
    u16* idx = (u16*)(h2 + (size_t)NG * NN * 16);     // 4 MB (reused by both kNNs)
    float* partial = (float*)(idx + (size_t)NG * NN * KK);  // 512*48 floats

    knn1<<<NG * 8, 256, 0, stream>>>(x, idx);
    conv1<<<NG * 4, 256, 0, stream>>>(x, idx, W1a, b1a, W2a, b2a, h1);
    knn2<<<NG * 8, 256, 0, stream>>>(h1, idx);
    conv2<<<NG * 4, 256, 0, stream>>>(h1, idx, W1b, b1b, W2b, b2b, h2);
    post_pool<<<NG * 4, 256, 0, stream>>>(x, h1, h2, Wp1, bp1, Wp2, bp2, partial);
    finalize<<<NG, 128, 0, stream>>>(partial, Wr1, br1, Wr2, br2, out);
}